// Round 1
// baseline (575.030 us; speedup 1.0000x reference)
//
#include <hip/hip_runtime.h>

#define SINGLE_DIM 256
#define PAIR_DIM   64
#define MAX_REL    32
#define LN_EPS     1e-5f
#define N_FIXED    1024

// ---------------------------------------------------------------------------
// Kernel A: proj[row][c] for c in [0,128): c<64 -> s@W_i + b, c>=64 -> s@W_j
// rows = B*N. One block handles 4 rows; thread t covers col4=(t&31)*4, row=t>>5.
// ---------------------------------------------------------------------------
__global__ __launch_bounds__(128) void proj_kernel(
    const float* __restrict__ s,     // (B*N, 256)
    const float* __restrict__ W,     // (512, 64) = [W_i; W_j]
    const float* __restrict__ bias,  // (64,)
    float* __restrict__ proj)        // (B*N, 128) = [pi+b | pj]
{
    __shared__ float lds[4][SINGLE_DIM];
    const int row0 = blockIdx.x * 4;
    const int t = threadIdx.x;

    // stage 4 rows (4 KB) into LDS: 1024 floats = 256 float4, 128 threads
    {
        const float4* src = (const float4*)(s + (size_t)row0 * SINGLE_DIM);
        float4* dst = (float4*)(&lds[0][0]);
        dst[t]       = src[t];
        dst[t + 128] = src[t + 128];
    }
    __syncthreads();

    const int c4   = (t & 31) * 4;   // col0 in [0,128)
    const int row  = t >> 5;         // 0..3
    const int half = c4 >> 6;        // 0 = i-proj, 1 = j-proj
    const int p0   = c4 & 63;
    const float* Wbase = W + half * (SINGLE_DIM * PAIR_DIM) + p0;
    const float* srow  = lds[row];

    float4 acc = {0.f, 0.f, 0.f, 0.f};
    #pragma unroll
    for (int d = 0; d < SINGLE_DIM; d += 4) {
        float4 s4 = *(const float4*)(srow + d);
        float4 w0 = *(const float4*)(Wbase + (d + 0) * PAIR_DIM);
        float4 w1 = *(const float4*)(Wbase + (d + 1) * PAIR_DIM);
        float4 w2 = *(const float4*)(Wbase + (d + 2) * PAIR_DIM);
        float4 w3 = *(const float4*)(Wbase + (d + 3) * PAIR_DIM);
        acc.x += s4.x * w0.x; acc.y += s4.x * w0.y; acc.z += s4.x * w0.z; acc.w += s4.x * w0.w;
        acc.x += s4.y * w1.x; acc.y += s4.y * w1.y; acc.z += s4.y * w1.z; acc.w += s4.y * w1.w;
        acc.x += s4.z * w2.x; acc.y += s4.z * w2.y; acc.z += s4.z * w2.z; acc.w += s4.z * w2.w;
        acc.x += s4.w * w3.x; acc.y += s4.w * w3.y; acc.z += s4.w * w3.z; acc.w += s4.w * w3.w;
    }
    if (half == 0) {
        float4 b4 = *(const float4*)(bias + p0);
        acc.x += b4.x; acc.y += b4.y; acc.z += b4.z; acc.w += b4.w;
    }
    *(float4*)(proj + (size_t)(row0 + row) * 128 + c4) = acc;
}

// ---------------------------------------------------------------------------
// Kernel B: one 16-lane group per (b,i,j) pair; lane covers 4 consecutive p.
// x = pi + pj (bias folded into pi); LayerNorm over 64 p via shuffle reduce;
// *gamma+beta; ReLU; + embed[clip(j-i)+32]; float4 store.
// Block = 256 threads = 16 pairs.
// ---------------------------------------------------------------------------
__global__ __launch_bounds__(256) void pair_kernel(
    const float* __restrict__ proj,   // (B*N, 128)
    const float* __restrict__ gamma,  // (64,)
    const float* __restrict__ beta,   // (64,)
    const float* __restrict__ embed,  // (65, 64)
    float* __restrict__ out)          // (B, N, N, 64)
{
    const int t = threadIdx.x;
    const int pairIdx = blockIdx.x * 16 + (t >> 4);
    const int p0 = (t & 15) * 4;

    const int j  = pairIdx & (N_FIXED - 1);
    const int bi = pairIdx >> 10;          // b*N + i   (N = 1024)
    const int i  = bi & (N_FIXED - 1);
    const int b  = bi >> 10;

    const float4 pi4 = *(const float4*)(proj + (size_t)bi * 128 + p0);
    const float4 pj4 = *(const float4*)(proj + (size_t)(b * N_FIXED + j) * 128 + 64 + p0);

    float4 v;
    v.x = pi4.x + pj4.x;
    v.y = pi4.y + pj4.y;
    v.z = pi4.z + pj4.z;
    v.w = pi4.w + pj4.w;

    float s  = v.x + v.y + v.z + v.w;
    float ss = v.x * v.x + v.y * v.y + v.z * v.z + v.w * v.w;
    #pragma unroll
    for (int mask = 1; mask < 16; mask <<= 1) {
        s  += __shfl_xor(s,  mask, 64);
        ss += __shfl_xor(ss, mask, 64);
    }
    const float mean = s * (1.f / PAIR_DIM);
    const float var  = ss * (1.f / PAIR_DIM) - mean * mean;
    const float rstd = rsqrtf(var + LN_EPS);

    const float4 g4 = *(const float4*)(gamma + p0);
    const float4 b4 = *(const float4*)(beta + p0);

    int rel = j - i;
    rel = (rel < -MAX_REL) ? -MAX_REL : (rel > MAX_REL ? MAX_REL : rel);
    rel += MAX_REL;
    const float4 e4 = *(const float4*)(embed + rel * PAIR_DIM + p0);

    float4 o;
    o.x = fmaxf((v.x - mean) * rstd * g4.x + b4.x, 0.f) + e4.x;
    o.y = fmaxf((v.y - mean) * rstd * g4.y + b4.y, 0.f) + e4.y;
    o.z = fmaxf((v.z - mean) * rstd * g4.z + b4.z, 0.f) + e4.z;
    o.w = fmaxf((v.w - mean) * rstd * g4.w + b4.w, 0.f) + e4.w;

    *(float4*)(out + (size_t)pairIdx * PAIR_DIM + p0) = o;
}

extern "C" void kernel_launch(void* const* d_in, const int* in_sizes, int n_in,
                              void* d_out, int out_size, void* d_ws, size_t ws_size,
                              hipStream_t stream) {
    const float* s     = (const float*)d_in[0];   // (B, N, 256)
    const float* W     = (const float*)d_in[1];   // (512, 64)
    const float* bias  = (const float*)d_in[2];   // (64,)
    const float* gamma = (const float*)d_in[3];   // (64,)
    const float* beta  = (const float*)d_in[4];   // (64,)
    const float* embed = (const float*)d_in[5];   // (65, 64)
    float* out  = (float*)d_out;
    float* proj = (float*)d_ws;                   // (B*N, 128) = 1 MB

    const int BN = in_sizes[0] / SINGLE_DIM;      // B*N = 2048

    proj_kernel<<<BN / 4, 128, 0, stream>>>(s, W, bias, proj);

    const int pairs = BN * N_FIXED;               // 2,097,152
    pair_kernel<<<pairs / 16, 256, 0, stream>>>(proj, gamma, beta, embed, out);
}

// Round 3
// 539.627 us; speedup vs baseline: 1.0656x; 1.0656x over previous
//
#include <hip/hip_runtime.h>

#define SINGLE_DIM 256
#define PAIR_DIM   64
#define MAX_REL    32
#define LN_EPS     1e-5f
#define N_FIXED    1024

typedef float vfloat4 __attribute__((ext_vector_type(4)));

// ---------------------------------------------------------------------------
// Kernel A: proj[row][c], c in [0,128): c<64 -> s@W_i + bias, c>=64 -> s@W_j
// One block = 2 rows x 128 cols = 256 threads, one output element per thread.
// s rows staged in LDS (wave-uniform broadcast reads); W stays in L1/L2.
// 1024 blocks = 4096 waves -> 4 waves/SIMD (vs 1 before).
// ---------------------------------------------------------------------------
__global__ __launch_bounds__(256) void proj_kernel(
    const float* __restrict__ s,     // (B*N, 256)
    const float* __restrict__ W,     // (512, 64) = [W_i; W_j]
    const float* __restrict__ bias,  // (64,)
    float* __restrict__ proj)        // (B*N, 128) = [pi+b | pj]
{
    __shared__ float lds[2][SINGLE_DIM];
    const int row0 = blockIdx.x * 2;
    const int t = threadIdx.x;

    // stage 2 rows (512 floats = 256 float2)
    ((float2*)(&lds[0][0]))[t] = ((const float2*)(s + (size_t)row0 * SINGLE_DIM))[t];
    __syncthreads();

    const int row  = t >> 7;         // 0..1 (wave-uniform)
    const int c    = t & 127;        // 0..127
    const int half = c >> 6;         // wave-uniform
    const int p    = c & 63;

    const float* wcol = W + half * (SINGLE_DIM * PAIR_DIM) + p;
    const float* srow = lds[row];

    float acc = (half == 0) ? bias[p] : 0.f;
    #pragma unroll 8
    for (int d = 0; d < SINGLE_DIM; ++d)
        acc += srow[d] * wcol[d * PAIR_DIM];

    proj[(size_t)(row0 + row) * 128 + c] = acc;
}

// ---------------------------------------------------------------------------
// Kernel B: 16-lane group per (b,i) x 4 j's (j stride 16 for store coalescing).
// Lane covers 4 consecutive p. 4 independent shuffle-reduce chains per wave
// hide ds_swizzle latency. Non-temporal stores (out never re-read).
// Block = 256 threads = 16 groups; block covers 64 consecutive j of one i.
// ---------------------------------------------------------------------------
__global__ __launch_bounds__(256) void pair_kernel(
    const float* __restrict__ proj,   // (B*N, 128)
    const float* __restrict__ gamma,  // (64,)
    const float* __restrict__ beta,   // (64,)
    const float* __restrict__ embed,  // (65, 64)
    float* __restrict__ out)          // (B, N, N, 64)
{
    const int t  = threadIdx.x;
    const int g  = t >> 4;             // group 0..15
    const int p0 = (t & 15) * 4;
    const int bid = blockIdx.x;
    const int bi    = bid >> 4;        // row index b*N + i
    const int jbase = (bid & 15) * 64 + g;   // j_k = jbase + 16*k
    const int i = bi & (N_FIXED - 1);
    const int b = bi >> 10;

    const float4 pi4 = *(const float4*)(proj + (size_t)bi * 128 + p0);
    const float4 g4  = *(const float4*)(gamma + p0);
    const float4 b4  = *(const float4*)(beta + p0);

    float4 v[4];
    float  s[4], ss[4];
    #pragma unroll
    for (int k = 0; k < 4; ++k) {
        const int j = jbase + 16 * k;
        const float4 pj4 = *(const float4*)(proj + (size_t)(b * N_FIXED + j) * 128 + 64 + p0);
        v[k].x = pi4.x + pj4.x;
        v[k].y = pi4.y + pj4.y;
        v[k].z = pi4.z + pj4.z;
        v[k].w = pi4.w + pj4.w;
        s[k]  = v[k].x + v[k].y + v[k].z + v[k].w;
        ss[k] = v[k].x * v[k].x + v[k].y * v[k].y + v[k].z * v[k].z + v[k].w * v[k].w;
    }

    #pragma unroll
    for (int mask = 1; mask < 16; mask <<= 1) {
        #pragma unroll
        for (int k = 0; k < 4; ++k) {
            s[k]  += __shfl_xor(s[k],  mask, 64);
            ss[k] += __shfl_xor(ss[k], mask, 64);
        }
    }

    #pragma unroll
    for (int k = 0; k < 4; ++k) {
        const int j = jbase + 16 * k;
        const float mean = s[k] * (1.f / PAIR_DIM);
        const float var  = ss[k] * (1.f / PAIR_DIM) - mean * mean;
        const float rstd = rsqrtf(var + LN_EPS);

        int rel = j - i;
        rel = (rel < -MAX_REL) ? -MAX_REL : (rel > MAX_REL ? MAX_REL : rel);
        rel += MAX_REL;
        const float4 e4 = *(const float4*)(embed + rel * PAIR_DIM + p0);

        vfloat4 o;
        o.x = fmaxf((v[k].x - mean) * rstd * g4.x + b4.x, 0.f) + e4.x;
        o.y = fmaxf((v[k].y - mean) * rstd * g4.y + b4.y, 0.f) + e4.y;
        o.z = fmaxf((v[k].z - mean) * rstd * g4.z + b4.z, 0.f) + e4.z;
        o.w = fmaxf((v[k].w - mean) * rstd * g4.w + b4.w, 0.f) + e4.w;

        __builtin_nontemporal_store(o,
            (vfloat4*)(out + ((size_t)bi * N_FIXED + j) * PAIR_DIM + p0));
    }
}

extern "C" void kernel_launch(void* const* d_in, const int* in_sizes, int n_in,
                              void* d_out, int out_size, void* d_ws, size_t ws_size,
                              hipStream_t stream) {
    const float* s     = (const float*)d_in[0];   // (B, N, 256)
    const float* W     = (const float*)d_in[1];   // (512, 64)
    const float* bias  = (const float*)d_in[2];   // (64,)
    const float* gamma = (const float*)d_in[3];   // (64,)
    const float* beta  = (const float*)d_in[4];   // (64,)
    const float* embed = (const float*)d_in[5];   // (65, 64)
    float* out  = (float*)d_out;
    float* proj = (float*)d_ws;                   // (B*N, 128) = 1 MB

    const int BN = in_sizes[0] / SINGLE_DIM;      // B*N = 2048

    proj_kernel<<<BN / 2, 256, 0, stream>>>(s, W, bias, proj);

    const int blocks = BN * (N_FIXED / 64);       // 32768
    pair_kernel<<<blocks, 256, 0, stream>>>(proj, gamma, beta, embed, out);
}